// Round 6
// baseline (1118.962 us; speedup 1.0000x reference)
//
#include <hip/hip_runtime.h>

typedef int   v4i __attribute__((ext_vector_type(4)));
typedef int  v16i __attribute__((ext_vector_type(16)));
typedef float v4f __attribute__((ext_vector_type(4)));

#define TT 1024
#define DD 256
#define HH 512
#define CB 32
#define CM (CB*TT)   // 32768 rows per chunk

__device__ __forceinline__ double shfl_xor_d(double x, int m) {
    union { double d; int u[2]; } a; a.d = x;
    a.u[0] = __shfl_xor(a.u[0], m);
    a.u[1] = __shfl_xor(a.u[1], m);
    return a.d;
}

// ---------------------------------------------------------------------------
// prep_w: split W1 [512][256] and W2 [256][512] into 5 signed-digit i8 planes.
// w = sum_j d_j * 2^(-10-7j), truncation digits, |d|<=127. Row-major kept.
// ---------------------------------------------------------------------------
__global__ __launch_bounds__(256) void prep_w_k(const float* __restrict__ W1,
                                                const float* __restrict__ W2,
                                                signed char* __restrict__ W1p,
                                                signed char* __restrict__ W2p) {
    int i = blockIdx.x * 256 + threadIdx.x;   // 0..131071
    {
        double a = (double)W1[i];
        double inv = 1024.0, s = 1.0 / 1024.0;
#pragma unroll
        for (int p = 0; p < 5; ++p) {
            int d = (int)(a * inv);
            a -= d * s;
            W1p[(size_t)p * 131072 + i] = (signed char)d;
            inv *= 128.0; s *= (1.0 / 128.0);
        }
    }
    {
        double a = (double)W2[i];
        double inv = 1024.0, s = 1.0 / 1024.0;
#pragma unroll
        for (int p = 0; p < 5; ++p) {
            int d = (int)(a * inv);
            a -= d * s;
            W2p[(size_t)p * 131072 + i] = (signed char)d;
            inv *= 128.0; s *= (1.0 / 128.0);
        }
    }
}

// ---------------------------------------------------------------------------
// GEMM1: H = x @ W1^T + b1 -> LayerNorm(512). Exact Ozaki i8 (15 pairs,
// 5 i32 banks). Block 32 rows x 512 cols, 1024 thr = 16 waves (1m x 16n),
// wave tile 32x32 -> acc[5][16] = 80 AGPR -> 4 waves/SIMD at <=128 regs.
// A: x split to 5 digit planes in-kernel (exact f32 ops), swizzled LDS,
// staged once (one barrier). B: direct global->VGPR per K=32 slice from
// L2-resident W1p (640 KB/block = B loaded exactly once per block).
// Loop: for ksl(8): load 5 A-frags + 5 B-frags -> 15 MFMAs.
// ---------------------------------------------------------------------------
__global__ __launch_bounds__(1024, 4) void gemm1_i8(
    const float* __restrict__ X, const signed char* __restrict__ W1p,
    const float* __restrict__ b1, const float* __restrict__ g1,
    const float* __restrict__ be1, double* __restrict__ Hn) {
    __shared__ signed char Asm[5 * 8192];       // 40960 B
    __shared__ double RS[16][32], RQ[16][32];
    __shared__ double MUs[32], IVs[32];

    const int tid = threadIdx.x;
    const int wave = tid >> 6, lane = tid & 63, lrow = lane & 31, lhalf = lane >> 5;
    const int m0 = blockIdx.x * 32;

    // ---- A stage: load x tile [32][256] f32, split to 5 i8 planes ----
    {
        const int r = tid >> 5;             // 0..31
        const int k0 = (tid & 31) * 8;      // element offset in row
        const float* xp = X + (size_t)(m0 + r) * DD + k0;
        float xe[8];
        *(v4f*)(xe + 0) = __builtin_nontemporal_load((const v4f*)(xp + 0));
        *(v4f*)(xe + 4) = __builtin_nontemporal_load((const v4f*)(xp + 4));
        int pk[5][2];
#pragma unroll
        for (int q = 0; q < 2; ++q)
#pragma unroll
            for (int e = 0; e < 4; ++e) {
                float a = xe[q * 4 + e];
                float inv = 8.0f, s = 0.125f;
#pragma unroll
                for (int p = 0; p < 5; ++p) {
                    int d = (int)(a * inv);       // exact: pow2 scale + trunc
                    a -= (float)d * s;            // exact cancellation
                    int byte = (d & 255) << (8 * e);
                    if (e == 0) pk[p][q] = byte; else pk[p][q] |= byte;
                    inv *= 128.0f; s *= (1.0f / 128.0f);
                }
            }
        const int swz = k0 ^ ((r & 15) << 4);
#pragma unroll
        for (int p = 0; p < 5; ++p)
            *(int2*)&Asm[p * 8192 + r * 256 + swz] = make_int2(pk[p][0], pk[p][1]);
    }

    v16i acc[5];
#pragma unroll
    for (int g = 0; g < 5; ++g)
#pragma unroll
        for (int r = 0; r < 16; ++r) acc[g][r] = 0;

    // per-lane B base pointer: column h = wave*32 + lrow
    const signed char* bbase = W1p + (size_t)(wave * 32 + lrow) * 256 + lhalf * 16;

    __syncthreads();   // A ready

    const int abase = lrow * 256;
    const int aswz = (lrow & 15) << 4;
#pragma unroll
    for (int ksl = 0; ksl < 8; ++ksl) {           // K=32 slices
        const int koff = (ksl * 32 + lhalf * 16) ^ aswz;
        v4i bf[5];
#pragma unroll
        for (int j = 0; j < 5; ++j)
            bf[j] = *(const v4i*)(bbase + (size_t)j * 131072 + ksl * 32);
        v4i af[5];
#pragma unroll
        for (int i = 0; i < 5; ++i)
            af[i] = *(const v4i*)&Asm[i * 8192 + abase + koff];
#pragma unroll
        for (int j = 0; j < 5; ++j)
#pragma unroll
            for (int i = 0; i + j < 5; ++i)
                acc[i + j] = __builtin_amdgcn_mfma_i32_32x32x32_i8(
                    af[i], bf[j], acc[i + j], 0, 0, 0);
    }

    // ---- epilogue: exact recombine -> fp64, bias, LayerNorm, store ----
    const double scl[5] = {0x1p-13, 0x1p-20, 0x1p-27, 0x1p-34, 0x1p-41};
    const int col = wave * 32 + lrow;
    double vv[16];
    {
        double bcol = (double)b1[col];
#pragma unroll
        for (int r = 0; r < 16; ++r) {
            double t = 0.0;
#pragma unroll
            for (int g = 0; g < 5; ++g) t = fma((double)acc[g][r], scl[g], t);
            vv[r] = t + bcol;
        }
    }
    double ps[16], pq[16];
#pragma unroll
    for (int r = 0; r < 16; ++r) { ps[r] = vv[r]; pq[r] = vv[r] * vv[r]; }
#pragma unroll
    for (int m = 1; m < 32; m <<= 1)
#pragma unroll
        for (int r = 0; r < 16; ++r) {
            ps[r] += shfl_xor_d(ps[r], m);
            pq[r] += shfl_xor_d(pq[r], m);
        }
    if (lrow == 0) {
#pragma unroll
        for (int r = 0; r < 16; ++r) {
            int rw = (r & 3) + 8 * (r >> 2) + 4 * lhalf;
            RS[wave][rw] = ps[r];
            RQ[wave][rw] = pq[r];
        }
    }
    __syncthreads();
    if (tid < 32) {
        double s = 0.0, q = 0.0;
#pragma unroll
        for (int w = 0; w < 16; ++w) { s += RS[w][tid]; q += RQ[w][tid]; }
        double mu = s * (1.0 / 512.0);
        double var = q * (1.0 / 512.0) - mu * mu;
        MUs[tid] = mu;
        IVs[tid] = 1.0 / sqrt(var + 1e-5);
    }
    __syncthreads();
    {
        double gg = (double)g1[col], bb2 = (double)be1[col];
#pragma unroll
        for (int r = 0; r < 16; ++r) {
            int rw = (r & 3) + 8 * (r >> 2) + 4 * lhalf;
            double o = (vv[r] - MUs[rw]) * IVs[rw] * gg + bb2;
            __builtin_nontemporal_store(o, &Hn[(size_t)(m0 + rw) * 512 + col]);
        }
    }
}

// ---------------------------------------------------------------------------
// GEMM2: Y = S @ W2^T + b2 -> LayerNorm(256). A = spikes (single exact
// plane) in swizzled LDS; B = 5 W2 planes direct global->VGPR. j-major:
// one i32 bank live (32 regs), retired into f64 vv after each plane.
// Block 64 x 256, 512 thr = 8 waves (2m x 4n), wave tile 32x64 (nt=2).
// ---------------------------------------------------------------------------
__global__ __launch_bounds__(512, 2) void gemm2_i8(
    const signed char* __restrict__ S, const signed char* __restrict__ W2p,
    const float* __restrict__ b2, const float* __restrict__ g2,
    const float* __restrict__ be2, double* __restrict__ Yn) {
    __shared__ signed char Asm[64 * 512];       // 32768 B
    __shared__ double RS[4][64], RQ[4][64];
    __shared__ double MUs[64], IVs[64];

    const int tid = threadIdx.x;
    const int wave = tid >> 6, lane = tid & 63, lrow = lane & 31, lhalf = lane >> 5;
    const int wm = wave >> 2, wn = wave & 3;
    const int m0 = blockIdx.x * 64;

    // ---- A stage: spikes [64][512], swizzled ----
    {
        const int r = tid >> 3, k0 = (tid & 7) * 64;
#pragma unroll
        for (int q = 0; q < 4; ++q) {
            int k = k0 + q * 16;
            v4i v = __builtin_nontemporal_load(
                (const v4i*)(S + (size_t)(m0 + r) * 512 + k));
            *(v4i*)&Asm[r * 512 + (k ^ ((r & 15) << 4))] = v;
        }
    }

    const signed char* bb0 = W2p + (size_t)(wn * 64 + lrow) * 512 + lhalf * 16;
    const signed char* bb1 = bb0 + 32 * 512;

    double vv[2][16];
#pragma unroll
    for (int nt = 0; nt < 2; ++nt)
#pragma unroll
        for (int r = 0; r < 16; ++r) vv[nt][r] = 0.0;

    __syncthreads();

    const int arow = wm * 32 + lrow;
    const int abase = arow * 512;
    const int aswz = (arow & 15) << 4;
    const double scl[5] = {0x1p-10, 0x1p-17, 0x1p-24, 0x1p-31, 0x1p-38};
#pragma unroll
    for (int j = 0; j < 5; ++j) {
        v16i bank0, bank1;
#pragma unroll
        for (int r = 0; r < 16; ++r) { bank0[r] = 0; bank1[r] = 0; }
        const size_t joff = (size_t)j * 131072;
#pragma unroll
        for (int ksl = 0; ksl < 16; ++ksl) {      // K=32 slices of K=512
            v4i b0 = *(const v4i*)(bb0 + joff + ksl * 32);
            v4i b1 = *(const v4i*)(bb1 + joff + ksl * 32);
            v4i a = *(const v4i*)&Asm[abase + ((ksl * 32 + lhalf * 16) ^ aswz)];
            bank0 = __builtin_amdgcn_mfma_i32_32x32x32_i8(a, b0, bank0, 0, 0, 0);
            bank1 = __builtin_amdgcn_mfma_i32_32x32x32_i8(a, b1, bank1, 0, 0, 0);
        }
#pragma unroll
        for (int r = 0; r < 16; ++r) {
            vv[0][r] = fma((double)bank0[r], scl[j], vv[0][r]);
            vv[1][r] = fma((double)bank1[r], scl[j], vv[1][r]);
        }
    }

    int colc[2];
#pragma unroll
    for (int nt = 0; nt < 2; ++nt) {
        colc[nt] = wn * 64 + nt * 32 + lrow;
        double bcol = (double)b2[colc[nt]];
#pragma unroll
        for (int r = 0; r < 16; ++r) vv[nt][r] += bcol;
    }
    double ps[16], pq[16];
#pragma unroll
    for (int r = 0; r < 16; ++r) {
        ps[r] = vv[0][r] + vv[1][r];
        pq[r] = vv[0][r] * vv[0][r] + vv[1][r] * vv[1][r];
    }
#pragma unroll
    for (int m = 1; m < 32; m <<= 1)
#pragma unroll
        for (int r = 0; r < 16; ++r) {
            ps[r] += shfl_xor_d(ps[r], m);
            pq[r] += shfl_xor_d(pq[r], m);
        }
    if (lrow == 0) {
#pragma unroll
        for (int r = 0; r < 16; ++r) {
            int rw = wm * 32 + (r & 3) + 8 * (r >> 2) + 4 * lhalf;
            RS[wn][rw] = ps[r];
            RQ[wn][rw] = pq[r];
        }
    }
    __syncthreads();
    if (tid < 64) {
        double s = 0.0, q = 0.0;
#pragma unroll
        for (int w = 0; w < 4; ++w) { s += RS[w][tid]; q += RQ[w][tid]; }
        double mu = s * (1.0 / 256.0);
        double var = q * (1.0 / 256.0) - mu * mu;
        MUs[tid] = mu;
        IVs[tid] = 1.0 / sqrt(var + 1e-5);
    }
    __syncthreads();
#pragma unroll
    for (int nt = 0; nt < 2; ++nt) {
        int col = colc[nt];
        double gg = (double)g2[col], bb2v = (double)be2[col];
#pragma unroll
        for (int r = 0; r < 16; ++r) {
            int rw = wm * 32 + (r & 3) + 8 * (r >> 2) + 4 * lhalf;
            double o = (vv[nt][r] - MUs[rw]) * IVs[rw] * gg + bb2v;
            __builtin_nontemporal_store(o, &Yn[(size_t)(m0 + rw) * 256 + col]);
        }
    }
}

// ---------------------------------------------------------------------------
// LIF1: fp64 recurrence over T, one lane per (b,h), depth-3 group prefetch.
// ---------------------------------------------------------------------------
__global__ __launch_bounds__(64) void lif1_k(const double* __restrict__ Hn,
                                             signed char* __restrict__ S) {
    int b = blockIdx.x >> 3;
    int h = (blockIdx.x & 7) * 64 + threadIdx.x;
    const double* src = Hn + (size_t)b * TT * HH + h;
    signed char* dst = S + (size_t)b * TT * HH + h;
    double v = 0.0;
    double buf[4][16];
#pragma unroll
    for (int gg = 0; gg < 3; ++gg)
#pragma unroll
        for (int t = 0; t < 16; ++t)
            buf[gg][t] = __builtin_nontemporal_load(&src[(size_t)(gg * 16 + t) * HH]);
    for (int g4 = 0; g4 < 64; g4 += 4) {
#pragma unroll
        for (int u = 0; u < 4; ++u) {
            int g = g4 + u;
            if (g + 3 < 64) {
#pragma unroll
                for (int t = 0; t < 16; ++t)
                    buf[(u + 3) & 3][t] =
                        __builtin_nontemporal_load(&src[(size_t)((g + 3) * 16 + t) * HH]);
            }
#pragma unroll
            for (int t = 0; t < 16; ++t) {
                v += (buf[u][t] - v) * 0.5;
                bool sp = (v >= 1.0);
                dst[(size_t)(g * 16 + t) * HH] = sp ? 1 : 0;
                if (sp) v = 0.0;
            }
        }
    }
}

// ---------------------------------------------------------------------------
// LIF2 + residual: out = x + spike, fp64 recurrence, depth-3 prefetch.
// ---------------------------------------------------------------------------
__global__ __launch_bounds__(64) void lif2_k(const double* __restrict__ Yn,
                                             const float* __restrict__ X,
                                             float* __restrict__ out) {
    int b = blockIdx.x >> 2;
    int d = (blockIdx.x & 3) * 64 + threadIdx.x;
    const double* src = Yn + (size_t)b * TT * DD + d;
    const float* xs = X + (size_t)b * TT * DD + d;
    float* dst = out + (size_t)b * TT * DD + d;
    double v = 0.0;
    double bufy[4][16];
    float bufx[4][16];
#pragma unroll
    for (int gg = 0; gg < 3; ++gg)
#pragma unroll
        for (int t = 0; t < 16; ++t) {
            bufy[gg][t] = __builtin_nontemporal_load(&src[(size_t)(gg * 16 + t) * DD]);
            bufx[gg][t] = __builtin_nontemporal_load(&xs[(size_t)(gg * 16 + t) * DD]);
        }
    for (int g4 = 0; g4 < 64; g4 += 4) {
#pragma unroll
        for (int u = 0; u < 4; ++u) {
            int g = g4 + u;
            if (g + 3 < 64) {
#pragma unroll
                for (int t = 0; t < 16; ++t) {
                    bufy[(u + 3) & 3][t] =
                        __builtin_nontemporal_load(&src[(size_t)((g + 3) * 16 + t) * DD]);
                    bufx[(u + 3) & 3][t] =
                        __builtin_nontemporal_load(&xs[(size_t)((g + 3) * 16 + t) * DD]);
                }
            }
#pragma unroll
            for (int t = 0; t < 16; ++t) {
                v += (bufy[u][t] - v) * 0.5;
                bool sp = (v >= 1.0);
                __builtin_nontemporal_store(bufx[u][t] + (sp ? 1.0f : 0.0f),
                                            &dst[(size_t)(g * 16 + t) * DD]);
                if (sp) v = 0.0;
            }
        }
    }
}

extern "C" void kernel_launch(void* const* d_in, const int* in_sizes, int n_in,
                              void* d_out, int out_size, void* d_ws, size_t ws_size,
                              hipStream_t stream) {
    const float* x   = (const float*)d_in[0];
    const float* W1  = (const float*)d_in[1];
    const float* b1  = (const float*)d_in[2];
    const float* g1  = (const float*)d_in[3];
    const float* be1 = (const float*)d_in[4];
    const float* W2  = (const float*)d_in[5];
    const float* b2  = (const float*)d_in[6];
    const float* g2  = (const float*)d_in[7];
    const float* be2 = (const float*)d_in[8];
    float* out = (float*)d_out;

    char* ws = (char*)d_ws;
    signed char* W1p = (signed char*)ws;                          // 640 KB
    signed char* W2p = (signed char*)(ws + (1ull << 20));         // 640 KB
    double*      Hn  = (double*)(ws + (2ull << 20));              // 128 MB
    signed char* Sb  = (signed char*)(ws + (130ull << 20));       // 16 MB
    double*      Yn  = (double*)(ws + (146ull << 20));            // 64 MB
    // total 210 MB

    prep_w_k<<<dim3(512), dim3(256), 0, stream>>>(W1, W2, W1p, W2p);

    for (int c = 0; c < 2; ++c) {
        const float* xc = x + (size_t)c * CM * DD;
        float* outc = out + (size_t)c * CM * DD;
        gemm1_i8<<<dim3(CM / 32), dim3(1024), 0, stream>>>(xc, W1p, b1, g1, be1, Hn);
        lif1_k<<<dim3(CB * 8), dim3(64), 0, stream>>>(Hn, Sb);
        gemm2_i8<<<dim3(CM / 64), dim3(512), 0, stream>>>(Sb, W2p, b2, g2, be2, Yn);
        lif2_k<<<dim3(CB * 4), dim3(64), 0, stream>>>(Yn, xc, outc);
    }
}

// Round 7
// 800.961 us; speedup vs baseline: 1.3970x; 1.3970x over previous
//
#include <hip/hip_runtime.h>

typedef int   v4i __attribute__((ext_vector_type(4)));
typedef int  v16i __attribute__((ext_vector_type(16)));
typedef float v4f __attribute__((ext_vector_type(4)));

#define TT 1024
#define DD 256
#define HH 512
#define CB 32
#define CM (CB*TT)   // 32768 rows per chunk

static __device__ __forceinline__ double shfl_xor_d(double x, int m) {
    union { double d; int u[2]; } a; a.d = x;
    a.u[0] = __shfl_xor(a.u[0], m);
    a.u[1] = __shfl_xor(a.u[1], m);
    return a.d;
}

// ---------------------------------------------------------------------------
// prep_w: split W1 [512][256] and W2 [256][512] into 5 signed-digit i8 planes.
// w = sum_j d_j * 2^(-10-7j), truncation digits, |d|<=127. Row-major kept.
// ---------------------------------------------------------------------------
__global__ __launch_bounds__(256) void prep_w_k(const float* __restrict__ W1,
                                                const float* __restrict__ W2,
                                                signed char* __restrict__ W1p,
                                                signed char* __restrict__ W2p) {
    int i = blockIdx.x * 256 + threadIdx.x;   // 0..131071
    {
        double a = (double)W1[i];
        double inv = 1024.0, s = 1.0 / 1024.0;
#pragma unroll
        for (int p = 0; p < 5; ++p) {
            int d = (int)(a * inv);
            a -= d * s;
            W1p[(size_t)p * 131072 + i] = (signed char)d;
            inv *= 128.0; s *= (1.0 / 128.0);
        }
    }
    {
        double a = (double)W2[i];
        double inv = 1024.0, s = 1.0 / 1024.0;
#pragma unroll
        for (int p = 0; p < 5; ++p) {
            int d = (int)(a * inv);
            a -= d * s;
            W2p[(size_t)p * 131072 + i] = (signed char)d;
            inv *= 128.0; s *= (1.0 / 128.0);
        }
    }
}

// ---------------------------------------------------------------------------
// GEMM1: raw H = x @ W1^T + b1 (f64) + per-row partial (sum,sumsq).
// Exact Ozaki i8: 15 plane pairs, 5 i32 banks (acc[5] = 80 regs).
// Block 512 thr = 8 waves (2m x 4n), tile 64 rows x 256 cols (grid x2 halves),
// 2 col-phases per wave reusing acc. A: 5 planes in swizzled LDS (80 KB),
// staged once. B: direct global->VGPR (L2-resident), 1-step prefetch.
// ---------------------------------------------------------------------------
__global__ __launch_bounds__(512, 2) void gemm1_i8(
    const float* __restrict__ X, const signed char* __restrict__ W1p,
    const float* __restrict__ b1, double* __restrict__ Hn,
    double* __restrict__ PS1, double* __restrict__ PQ1) {
    __shared__ signed char Asm[5 * 16384];          // 80 KB: [plane][64][256]
    __shared__ double RSs[4][64], RQs[4][64];       // 4 KB

    const int tid = threadIdx.x;
    const int wave = tid >> 6, lane = tid & 63, lrow = lane & 31, lhalf = lane >> 5;
    const int wm = wave >> 2, wn = wave & 3;
    const int ch = blockIdx.x;           // column half of H (0/1)
    const int m0 = blockIdx.y * 64;

    if (tid < 256) { (&RSs[0][0])[tid] = 0.0; (&RQs[0][0])[tid] = 0.0; }

    // ---- stage A: x[64][256] f32 -> 5 digit planes (exact), swizzled ----
    {
        const int r = tid >> 3, k0 = (tid & 7) * 32;
        const float* xp = X + (size_t)(m0 + r) * DD + k0;
        const int swz = (r & 15) << 4;
#pragma unroll
        for (int half = 0; half < 2; ++half) {
            float xe[16];
#pragma unroll
            for (int q = 0; q < 4; ++q)
                *(v4f*)(xe + q * 4) =
                    __builtin_nontemporal_load((const v4f*)(xp + half * 16 + q * 4));
            int pk[5][4];
#pragma unroll
            for (int q = 0; q < 4; ++q)
#pragma unroll
                for (int e = 0; e < 4; ++e) {
                    float a = xe[q * 4 + e];
                    float inv = 8.0f, s = 0.125f;
#pragma unroll
                    for (int p = 0; p < 5; ++p) {
                        int dg = (int)(a * inv);      // exact: pow2 scale + trunc
                        a -= (float)dg * s;           // exact cancellation
                        int byte = (dg & 255) << (8 * e);
                        if (e == 0) pk[p][q] = byte; else pk[p][q] |= byte;
                        inv *= 128.0f; s *= (1.0f / 128.0f);
                    }
                }
#pragma unroll
            for (int p = 0; p < 5; ++p)
                *(v4i*)&Asm[p * 16384 + r * 256 + ((k0 + half * 16) ^ swz)] =
                    *(const v4i*)&pk[p][0];
        }
    }

    const int colbase = ch * 256 + wn * 32 + lrow;
    const signed char* bptr = W1p + (size_t)colbase * 256 + lhalf * 16;

    v16i acc[5];
    v4i cbf[5];
#pragma unroll
    for (int j = 0; j < 5; ++j)
        cbf[j] = *(const v4i*)(bptr + (size_t)j * 131072);

    __syncthreads();   // A ready

    const double scl[5] = {0x1p-13, 0x1p-20, 0x1p-27, 0x1p-34, 0x1p-41};
    const int arow = wm * 32 + lrow;
    const int aswz = (arow & 15) << 4;

#pragma unroll
    for (int p = 0; p < 2; ++p) {
#pragma unroll
        for (int g = 0; g < 5; ++g)
#pragma unroll
            for (int r = 0; r < 16; ++r) acc[g][r] = 0;
#pragma unroll
        for (int ksl = 0; ksl < 8; ++ksl) {        // K=32 slices
            v4i nbf[5];
            const int s = p * 8 + ksl;
            if (s < 15) {
                const int np = (ksl == 7) ? p + 1 : p;
                const int nk = (ksl == 7) ? 0 : ksl + 1;
#pragma unroll
                for (int j = 0; j < 5; ++j)
                    nbf[j] = *(const v4i*)(bptr + (size_t)j * 131072 + np * 32768 + nk * 32);
            }
            v4i af[5];
#pragma unroll
            for (int i = 0; i < 5; ++i)
                af[i] = *(const v4i*)&Asm[i * 16384 + arow * 256 +
                                          ((ksl * 32 + lhalf * 16) ^ aswz)];
#pragma unroll
            for (int j = 0; j < 5; ++j)
#pragma unroll
                for (int i = 0; i + j < 5; ++i)
                    acc[i + j] = __builtin_amdgcn_mfma_i32_32x32x32_i8(
                        af[i], cbf[j], acc[i + j], 0, 0, 0);
#pragma unroll
            for (int j = 0; j < 5; ++j) cbf[j] = nbf[j];
        }
        // ---- retire phase p: exact recombine, raw store, row partials ----
        const int col = colbase + p * 128;
        const double bcol = (double)b1[col];
#pragma unroll
        for (int r = 0; r < 16; ++r) {
            double t = 0.0;
#pragma unroll
            for (int g = 0; g < 5; ++g) t = fma((double)acc[g][r], scl[g], t);
            const double hr = t + bcol;
            const int crow = (r & 3) + 8 * (r >> 2) + 4 * lhalf;
            __builtin_nontemporal_store(hr, &Hn[(size_t)(m0 + wm * 32 + crow) * HH + col]);
            double ps = hr, pq = hr * hr;
#pragma unroll
            for (int m = 1; m < 32; m <<= 1) {
                ps += shfl_xor_d(ps, m);
                pq += shfl_xor_d(pq, m);
            }
            if (lrow == 0) {
                RSs[wn][wm * 32 + crow] += ps;
                RQs[wn][wm * 32 + crow] += pq;
            }
        }
    }
    __syncthreads();
    if (tid < 64) {
        const double S = RSs[0][tid] + RSs[1][tid] + RSs[2][tid] + RSs[3][tid];
        const double Q = RQs[0][tid] + RQs[1][tid] + RQs[2][tid] + RQs[3][tid];
        PS1[(size_t)ch * CM + m0 + tid] = S;
        PQ1[(size_t)ch * CM + m0 + tid] = Q;
    }
}

// ---------------------------------------------------------------------------
// stats1_fin: per-row (mu, iv) for LN1 from the 2 col-half partials.
// ---------------------------------------------------------------------------
__global__ __launch_bounds__(256) void stats1_fin(const double* __restrict__ PS1,
                                                  const double* __restrict__ PQ1,
                                                  double2* __restrict__ MUIV1) {
    int row = blockIdx.x * 256 + threadIdx.x;
    double S = PS1[row] + PS1[CM + row];
    double Q = PQ1[row] + PQ1[CM + row];
    double mu = S * (1.0 / 512.0);
    double var = Q * (1.0 / 512.0) - mu * mu;
    MUIV1[row] = make_double2(mu, 1.0 / sqrt(var + 1e-5));
}

// ---------------------------------------------------------------------------
// LIF1: apply LN1 (mu,iv broadcast via LDS dbuf) + fp64 LIF recurrence -> S.
// 128 thr (h-quarter per block), data ring depth 3.
// ---------------------------------------------------------------------------
__global__ __launch_bounds__(128) void lif1_k(const double* __restrict__ Hn,
                                              const double2* __restrict__ MUIV,
                                              const float* __restrict__ g1,
                                              const float* __restrict__ be1,
                                              signed char* __restrict__ S) {
    const int b = blockIdx.x >> 2;
    const int h = (blockIdx.x & 3) * 128 + threadIdx.x;
    __shared__ double2 MI[4][16];
    const double* src = Hn + (size_t)b * TT * HH + h;
    signed char* dst = S + (size_t)b * TT * HH + h;
    const double gg = (double)g1[h], be = (double)be1[h];
    if (threadIdx.x < 48) {
        int gq = threadIdx.x >> 4, tt = threadIdx.x & 15;
        MI[gq][tt] = MUIV[(size_t)b * TT + gq * 16 + tt];
    }
    double buf[4][16];
#pragma unroll
    for (int gq = 0; gq < 3; ++gq)
#pragma unroll
        for (int t = 0; t < 16; ++t)
            buf[gq][t] = __builtin_nontemporal_load(&src[(size_t)(gq * 16 + t) * HH]);
    __syncthreads();
    double v = 0.0;
    for (int g4 = 0; g4 < 64; g4 += 4) {
#pragma unroll
        for (int u = 0; u < 4; ++u) {
            const int g = g4 + u;
            __syncthreads();
            if (g + 3 < 64) {
                if (threadIdx.x < 16)
                    MI[(g + 3) & 3][threadIdx.x] =
                        MUIV[(size_t)b * TT + (g + 3) * 16 + threadIdx.x];
#pragma unroll
                for (int t = 0; t < 16; ++t)
                    buf[(u + 3) & 3][t] =
                        __builtin_nontemporal_load(&src[(size_t)((g + 3) * 16 + t) * HH]);
            }
#pragma unroll
            for (int t = 0; t < 16; ++t) {
                const double2 mi = MI[g & 3][t];
                const double x = (buf[u][t] - mi.x) * mi.y * gg + be;
                v += (x - v) * 0.5;
                const bool sp = (v >= 1.0);
                dst[(size_t)(g * 16 + t) * HH] = sp ? 1 : 0;
                if (sp) v = 0.0;
            }
        }
    }
}

// ---------------------------------------------------------------------------
// GEMM2: raw Y = S @ W2^T + b2 (f64) + in-block (mu,iv) for LN2.
// A = spikes (1 exact plane) swizzled LDS; B = 5 W2 planes direct w/ prefetch.
// Block 512 thr, 64 rows x 256 cols (full row -> fused stats), 2 row-phases.
// ---------------------------------------------------------------------------
__global__ __launch_bounds__(512, 2) void gemm2_i8(
    const signed char* __restrict__ Sb, const signed char* __restrict__ W2p,
    const float* __restrict__ b2, double* __restrict__ Yn,
    double2* __restrict__ MUIV2) {
    __shared__ signed char Asm[64 * 512];        // 32 KB
    __shared__ double RSs[8][64], RQs[8][64];    // 8 KB

    const int tid = threadIdx.x;
    const int wave = tid >> 6, lane = tid & 63, lrow = lane & 31, lhalf = lane >> 5;
    const int m0 = blockIdx.x * 64;

    // ---- stage A (spikes) ----
    {
        const int r = tid >> 3, k0 = (tid & 7) * 64;
        const signed char* sp = Sb + (size_t)(m0 + r) * HH + k0;
        const int swz = (r & 15) << 4;
#pragma unroll
        for (int q = 0; q < 4; ++q) {
            v4i v = __builtin_nontemporal_load((const v4i*)(sp + q * 16));
            *(v4i*)&Asm[r * 512 + ((k0 + q * 16) ^ swz)] = v;
        }
    }

    const int col = wave * 32 + lrow;
    const signed char* bptr = W2p + (size_t)col * 512 + lhalf * 16;

    v16i acc[5];
    v4i cbf[5];
#pragma unroll
    for (int j = 0; j < 5; ++j) cbf[j] = *(const v4i*)(bptr + (size_t)j * 131072);

    __syncthreads();

    const double scl[5] = {0x1p-10, 0x1p-17, 0x1p-24, 0x1p-31, 0x1p-38};
#pragma unroll
    for (int p = 0; p < 2; ++p) {
#pragma unroll
        for (int g = 0; g < 5; ++g)
#pragma unroll
            for (int r = 0; r < 16; ++r) acc[g][r] = 0;
        const int arow = p * 32 + lrow;
        const int aswz = (arow & 15) << 4;
#pragma unroll
        for (int ksl = 0; ksl < 16; ++ksl) {     // K=32 slices of 512
            v4i nbf[5];
            const int s = p * 16 + ksl;
            if (s < 31) {
                const int nk = (ksl == 15) ? 0 : ksl + 1;
#pragma unroll
                for (int j = 0; j < 5; ++j)
                    nbf[j] = *(const v4i*)(bptr + (size_t)j * 131072 + nk * 32);
            }
            v4i a = *(const v4i*)&Asm[arow * 512 + ((ksl * 32 + lhalf * 16) ^ aswz)];
#pragma unroll
            for (int j = 0; j < 5; ++j)
                acc[j] = __builtin_amdgcn_mfma_i32_32x32x32_i8(a, cbf[j], acc[j], 0, 0, 0);
#pragma unroll
            for (int j = 0; j < 5; ++j) cbf[j] = nbf[j];
        }
        const double bcol = (double)b2[col];
#pragma unroll
        for (int r = 0; r < 16; ++r) {
            double t = 0.0;
#pragma unroll
            for (int g = 0; g < 5; ++g) t = fma((double)acc[g][r], scl[g], t);
            const double yr = t + bcol;
            const int crow = (r & 3) + 8 * (r >> 2) + 4 * lhalf;
            __builtin_nontemporal_store(yr, &Yn[(size_t)(m0 + p * 32 + crow) * DD + col]);
            double ps = yr, pq = yr * yr;
#pragma unroll
            for (int m = 1; m < 32; m <<= 1) {
                ps += shfl_xor_d(ps, m);
                pq += shfl_xor_d(pq, m);
            }
            if (lrow == 0) {
                RSs[wave][p * 32 + crow] = ps;
                RQs[wave][p * 32 + crow] = pq;
            }
        }
    }
    __syncthreads();
    if (tid < 64) {
        double Ssum = 0.0, Qsum = 0.0;
#pragma unroll
        for (int w = 0; w < 8; ++w) { Ssum += RSs[w][tid]; Qsum += RQs[w][tid]; }
        const double mu = Ssum * (1.0 / 256.0);
        const double var = Qsum * (1.0 / 256.0) - mu * mu;
        MUIV2[m0 + tid] = make_double2(mu, 1.0 / sqrt(var + 1e-5));
    }
}

// ---------------------------------------------------------------------------
// LIF2: apply LN2 + fp64 LIF + residual. out = x + spike.
// ---------------------------------------------------------------------------
__global__ __launch_bounds__(128) void lif2_k(const double* __restrict__ Yn,
                                              const double2* __restrict__ MUIV,
                                              const float* __restrict__ g2,
                                              const float* __restrict__ be2,
                                              const float* __restrict__ X,
                                              float* __restrict__ out) {
    const int b = blockIdx.x >> 1;
    const int d = (blockIdx.x & 1) * 128 + threadIdx.x;
    __shared__ double2 MI[4][16];
    const double* src = Yn + (size_t)b * TT * DD + d;
    const float* xs = X + (size_t)b * TT * DD + d;
    float* dst = out + (size_t)b * TT * DD + d;
    const double gg = (double)g2[d], be = (double)be2[d];
    if (threadIdx.x < 48) {
        int gq = threadIdx.x >> 4, tt = threadIdx.x & 15;
        MI[gq][tt] = MUIV[(size_t)b * TT + gq * 16 + tt];
    }
    double bufy[4][16];
    float bufx[4][16];
#pragma unroll
    for (int gq = 0; gq < 3; ++gq)
#pragma unroll
        for (int t = 0; t < 16; ++t) {
            bufy[gq][t] = __builtin_nontemporal_load(&src[(size_t)(gq * 16 + t) * DD]);
            bufx[gq][t] = __builtin_nontemporal_load(&xs[(size_t)(gq * 16 + t) * DD]);
        }
    __syncthreads();
    double v = 0.0;
    for (int g4 = 0; g4 < 64; g4 += 4) {
#pragma unroll
        for (int u = 0; u < 4; ++u) {
            const int g = g4 + u;
            __syncthreads();
            if (g + 3 < 64) {
                if (threadIdx.x < 16)
                    MI[(g + 3) & 3][threadIdx.x] =
                        MUIV[(size_t)b * TT + (g + 3) * 16 + threadIdx.x];
#pragma unroll
                for (int t = 0; t < 16; ++t) {
                    bufy[(u + 3) & 3][t] =
                        __builtin_nontemporal_load(&src[(size_t)((g + 3) * 16 + t) * DD]);
                    bufx[(u + 3) & 3][t] =
                        __builtin_nontemporal_load(&xs[(size_t)((g + 3) * 16 + t) * DD]);
                }
            }
#pragma unroll
            for (int t = 0; t < 16; ++t) {
                const double2 mi = MI[g & 3][t];
                const double x = (bufy[u][t] - mi.x) * mi.y * gg + be;
                v += (x - v) * 0.5;
                const bool sp = (v >= 1.0);
                __builtin_nontemporal_store(bufx[u][t] + (sp ? 1.0f : 0.0f),
                                            &dst[(size_t)(g * 16 + t) * DD]);
                if (sp) v = 0.0;
            }
        }
    }
}

extern "C" void kernel_launch(void* const* d_in, const int* in_sizes, int n_in,
                              void* d_out, int out_size, void* d_ws, size_t ws_size,
                              hipStream_t stream) {
    const float* x   = (const float*)d_in[0];
    const float* W1  = (const float*)d_in[1];
    const float* b1  = (const float*)d_in[2];
    const float* g1  = (const float*)d_in[3];
    const float* be1 = (const float*)d_in[4];
    const float* W2  = (const float*)d_in[5];
    const float* b2  = (const float*)d_in[6];
    const float* g2  = (const float*)d_in[7];
    const float* be2 = (const float*)d_in[8];
    float* out = (float*)d_out;

    char* ws = (char*)d_ws;
    signed char* W1p = (signed char*)ws;                             // 640 KB
    signed char* W2p = (signed char*)(ws + (1ull << 20));            // 640 KB
    double*      Hn  = (double*)(ws + (2ull << 20));                 // 128 MB
    signed char* Sb  = (signed char*)(ws + (130ull << 20));          // 16 MB
    double*      Yn  = (double*)(ws + (146ull << 20));               // 64 MB
    double*      PS1 = (double*)(ws + (210ull << 20));               // 512 KB
    double*      PQ1 = (double*)(ws + (210ull << 20) + (1ull << 19));// 512 KB
    double2*     MUIV1 = (double2*)(ws + (211ull << 20));            // 512 KB
    double2*     MUIV2 = (double2*)(ws + (211ull << 20) + (1ull << 19)); // 512 KB
    // total ~212 MB

    prep_w_k<<<dim3(512), dim3(256), 0, stream>>>(W1, W2, W1p, W2p);

    for (int c = 0; c < 2; ++c) {
        const float* xc = x + (size_t)c * CM * DD;
        float* outc = out + (size_t)c * CM * DD;
        gemm1_i8<<<dim3(2, CM / 64), dim3(512), 0, stream>>>(xc, W1p, b1, Hn, PS1, PQ1);
        stats1_fin<<<dim3(CM / 256), dim3(256), 0, stream>>>(PS1, PQ1, MUIV1);
        lif1_k<<<dim3(CB * 4), dim3(128), 0, stream>>>(Hn, MUIV1, g1, be1, Sb);
        gemm2_i8<<<dim3(CM / 64), dim3(512), 0, stream>>>(Sb, W2p, b2, Yn, MUIV2);
        lif2_k<<<dim3(CB * 2), dim3(128), 0, stream>>>(Yn, MUIV2, g2, be2, xc, outc);
    }
}

// Round 8
// 780.121 us; speedup vs baseline: 1.4343x; 1.0267x over previous
//
#include <hip/hip_runtime.h>

typedef int   v4i __attribute__((ext_vector_type(4)));
typedef int  v16i __attribute__((ext_vector_type(16)));
typedef float v4f __attribute__((ext_vector_type(4)));

#define TT 1024
#define DD 256
#define HH 512
#define CB 32
#define CM (CB*TT)   // 32768 rows per chunk

static __device__ __forceinline__ double shfl_xor_d(double x, int m) {
    union { double d; int u[2]; } a; a.d = x;
    a.u[0] = __shfl_xor(a.u[0], m);
    a.u[1] = __shfl_xor(a.u[1], m);
    return a.d;
}

// ---------------------------------------------------------------------------
// prep_w: split W1 [512][256] and W2 [256][512] into 5 signed-digit i8 planes.
// ---------------------------------------------------------------------------
__global__ __launch_bounds__(256) void prep_w_k(const float* __restrict__ W1,
                                                const float* __restrict__ W2,
                                                signed char* __restrict__ W1p,
                                                signed char* __restrict__ W2p) {
    int i = blockIdx.x * 256 + threadIdx.x;   // 0..131071
    {
        double a = (double)W1[i];
        double inv = 1024.0, s = 1.0 / 1024.0;
#pragma unroll
        for (int p = 0; p < 5; ++p) {
            int d = (int)(a * inv);
            a -= d * s;
            W1p[(size_t)p * 131072 + i] = (signed char)d;
            inv *= 128.0; s *= (1.0 / 128.0);
        }
    }
    {
        double a = (double)W2[i];
        double inv = 1024.0, s = 1.0 / 1024.0;
#pragma unroll
        for (int p = 0; p < 5; ++p) {
            int d = (int)(a * inv);
            a -= d * s;
            W2p[(size_t)p * 131072 + i] = (signed char)d;
            inv *= 128.0; s *= (1.0 / 128.0);
        }
    }
}

// ---------------------------------------------------------------------------
// split_x: x chunk [CM][256] f32 -> 5 digit planes i8 (exact pow2/trunc ops).
// ---------------------------------------------------------------------------
__global__ __launch_bounds__(256) void split_x_k(const float* __restrict__ xc,
                                                 signed char* __restrict__ Xp) {
    int gid = blockIdx.x * 256 + threadIdx.x;   // 0 .. CM*64-1
    int e0 = gid * 4;
    v4f xv = *(const v4f*)(xc + e0);
    int dg[4][5];
#pragma unroll
    for (int e = 0; e < 4; ++e) {
        float a = xv[e];
        float inv = 8.0f, s = 0.125f;
#pragma unroll
        for (int p = 0; p < 5; ++p) {
            int d = (int)(a * inv);
            a -= (float)d * s;
            dg[e][p] = d;
            inv *= 128.0f; s *= (1.0f / 128.0f);
        }
    }
#pragma unroll
    for (int p = 0; p < 5; ++p) {
        int pk = (dg[0][p] & 255) | ((dg[1][p] & 255) << 8) |
                 ((dg[2][p] & 255) << 16) | ((dg[3][p] & 255) << 24);
        *(int*)(Xp + (size_t)p * ((size_t)CM * 256) + e0) = pk;
    }
}

// ---------------------------------------------------------------------------
// GEMM1: raw H = x @ W1^T + b1 (f64) + per-wave row partials (sum,sumsq) to
// global. Exact Ozaki i8: 15 pairs, 5 i32 banks. Block 512 thr = 8 waves
// (2m x 4n), tile 64 rows x 256 cols (grid x2 col-halves), 2 col-phases.
// A: 5 planes from Xp staged once in swizzled LDS (exactly 80 KB ->
// 2 blocks/CU). B: direct global->VGPR, 1-step prefetch.
// ---------------------------------------------------------------------------
__global__ __launch_bounds__(512, 2) void gemm1_i8(
    const signed char* __restrict__ Xp, const signed char* __restrict__ W1p,
    const float* __restrict__ b1, double* __restrict__ Hn,
    double* __restrict__ PS1w, double* __restrict__ PQ1w) {
    __shared__ signed char Asm[5 * 16384];          // exactly 80 KB

    const int tid = threadIdx.x;
    const int wave = tid >> 6, lane = tid & 63, lrow = lane & 31, lhalf = lane >> 5;
    const int wm = wave >> 2, wn = wave & 3;
    const int ch = blockIdx.x;           // column half of H (0/1)
    const int m0 = blockIdx.y * 64;

    // ---- stage A: 5 planes x [64][256] from Xp, swizzled ----
    {
        const int r = tid >> 3, k0 = (tid & 7) * 32;
        const int swz = (r & 15) << 4;
#pragma unroll
        for (int p = 0; p < 5; ++p) {
            const signed char* sp = Xp + (size_t)p * ((size_t)CM * 256) +
                                    (size_t)(m0 + r) * 256 + k0;
            v4i v0 = *(const v4i*)(sp);
            v4i v1 = *(const v4i*)(sp + 16);
            *(v4i*)&Asm[p * 16384 + r * 256 + (k0 ^ swz)] = v0;
            *(v4i*)&Asm[p * 16384 + r * 256 + ((k0 + 16) ^ swz)] = v1;
        }
    }

    const int colbase = ch * 256 + wn * 32 + lrow;
    const signed char* bptr = W1p + (size_t)colbase * 256 + lhalf * 16;

    v16i acc[5];
    v4i cbf[5];
#pragma unroll
    for (int j = 0; j < 5; ++j)
        cbf[j] = *(const v4i*)(bptr + (size_t)j * 131072);

    __syncthreads();   // A ready

    const double scl[5] = {0x1p-13, 0x1p-20, 0x1p-27, 0x1p-34, 0x1p-41};
    const int arow = wm * 32 + lrow;
    const int aswz = (arow & 15) << 4;

#pragma unroll
    for (int p = 0; p < 2; ++p) {
#pragma unroll
        for (int g = 0; g < 5; ++g)
#pragma unroll
            for (int r = 0; r < 16; ++r) acc[g][r] = 0;
#pragma unroll
        for (int ksl = 0; ksl < 8; ++ksl) {        // K=32 slices
            v4i nbf[5];
            const int s = p * 8 + ksl;
            if (s < 15) {
                const int np = (ksl == 7) ? p + 1 : p;
                const int nk = (ksl == 7) ? 0 : ksl + 1;
#pragma unroll
                for (int j = 0; j < 5; ++j)
                    nbf[j] = *(const v4i*)(bptr + (size_t)j * 131072 + np * 32768 + nk * 32);
            }
            v4i af[5];
#pragma unroll
            for (int i = 0; i < 5; ++i)
                af[i] = *(const v4i*)&Asm[i * 16384 + arow * 256 +
                                          ((ksl * 32 + lhalf * 16) ^ aswz)];
#pragma unroll
            for (int j = 0; j < 5; ++j)
#pragma unroll
                for (int i = 0; i + j < 5; ++i)
                    acc[i + j] = __builtin_amdgcn_mfma_i32_32x32x32_i8(
                        af[i], cbf[j], acc[i + j], 0, 0, 0);
#pragma unroll
            for (int j = 0; j < 5; ++j) cbf[j] = nbf[j];
        }
        // ---- retire phase p: exact recombine, store, per-wave partials ----
        const int col = colbase + p * 128;
        const double bcol = (double)b1[col];
        const size_t qbase = (size_t)((ch * 2 + p) * 4 + wn) * CM + m0 + wm * 32;
#pragma unroll
        for (int r = 0; r < 16; ++r) {
            double t = 0.0;
#pragma unroll
            for (int g = 0; g < 5; ++g) t = fma((double)acc[g][r], scl[g], t);
            const double hr = t + bcol;
            const int crow = (r & 3) + 8 * (r >> 2) + 4 * lhalf;
            Hn[(size_t)(m0 + wm * 32 + crow) * HH + col] = hr;
            double ps = hr, pq = hr * hr;
#pragma unroll
            for (int m = 1; m < 32; m <<= 1) {
                ps += shfl_xor_d(ps, m);
                pq += shfl_xor_d(pq, m);
            }
            if (lrow == 0) {
                PS1w[qbase + crow] = ps;
                PQ1w[qbase + crow] = pq;
            }
        }
    }
}

// ---------------------------------------------------------------------------
// stats1_fin: per-row (mu, iv) for LN1 from the 16 per-wave partials.
// ---------------------------------------------------------------------------
__global__ __launch_bounds__(256) void stats1_fin(const double* __restrict__ PS1w,
                                                  const double* __restrict__ PQ1w,
                                                  double2* __restrict__ MUIV1) {
    int row = blockIdx.x * 256 + threadIdx.x;
    double S = 0.0, Q = 0.0;
#pragma unroll
    for (int q = 0; q < 16; ++q) {
        S += PS1w[(size_t)q * CM + row];
        Q += PQ1w[(size_t)q * CM + row];
    }
    double mu = S * (1.0 / 512.0);
    double var = Q * (1.0 / 512.0) - mu * mu;
    MUIV1[row] = make_double2(mu, 1.0 / sqrt(var + 1e-5));
}

// ---------------------------------------------------------------------------
// LIF1: apply LN1 (mu,iv ring in LDS) + fp64 LIF recurrence -> spikes.
// 64 thr/block, grid = 32 b x 8 h-groups = 256 blocks (all CUs busy).
// ---------------------------------------------------------------------------
__global__ __launch_bounds__(64) void lif1_k(const double* __restrict__ Hn,
                                             const double2* __restrict__ MUIV,
                                             const float* __restrict__ g1,
                                             const float* __restrict__ be1,
                                             signed char* __restrict__ S) {
    const int b = blockIdx.x >> 3;
    const int h = (blockIdx.x & 7) * 64 + threadIdx.x;
    __shared__ double2 MI[4][16];
    const double* src = Hn + (size_t)b * TT * HH + h;
    signed char* dst = S + (size_t)b * TT * HH + h;
    const double gg = (double)g1[h], be = (double)be1[h];
    if (threadIdx.x < 48)
        MI[threadIdx.x >> 4][threadIdx.x & 15] = MUIV[(size_t)b * TT + threadIdx.x];
    double buf[4][16];
#pragma unroll
    for (int gq = 0; gq < 3; ++gq)
#pragma unroll
        for (int t = 0; t < 16; ++t)
            buf[gq][t] = src[(size_t)(gq * 16 + t) * HH];
    __syncthreads();
    double v = 0.0;
    for (int g4 = 0; g4 < 64; g4 += 4) {
#pragma unroll
        for (int u = 0; u < 4; ++u) {
            const int g = g4 + u;
            __syncthreads();
            if (g + 3 < 64) {
                if (threadIdx.x < 16)
                    MI[(g + 3) & 3][threadIdx.x] =
                        MUIV[(size_t)b * TT + (g + 3) * 16 + threadIdx.x];
#pragma unroll
                for (int t = 0; t < 16; ++t)
                    buf[(u + 3) & 3][t] = src[(size_t)((g + 3) * 16 + t) * HH];
            }
#pragma unroll
            for (int t = 0; t < 16; ++t) {
                const double2 mi = MI[g & 3][t];
                const double x = (buf[u][t] - mi.x) * mi.y * gg + be;
                v += (x - v) * 0.5;
                const bool sp = (v >= 1.0);
                dst[(size_t)(g * 16 + t) * HH] = sp ? 1 : 0;
                if (sp) v = 0.0;
            }
        }
    }
}

// ---------------------------------------------------------------------------
// GEMM2: raw Y = S @ W2^T + b2 (f64) + in-block (mu,iv) for LN2.
// A = spikes (1 exact plane) swizzled LDS; B = 5 W2 planes direct w/ prefetch.
// Block 512 thr, 64 rows x 256 cols (full rows -> fused stats), 2 row-phases.
// ---------------------------------------------------------------------------
__global__ __launch_bounds__(512, 2) void gemm2_i8(
    const signed char* __restrict__ Sb, const signed char* __restrict__ W2p,
    const float* __restrict__ b2, double* __restrict__ Yn,
    double2* __restrict__ MUIV2) {
    __shared__ signed char Asm[64 * 512];        // 32 KB
    __shared__ double RSs[8][64], RQs[8][64];    // 8 KB

    const int tid = threadIdx.x;
    const int wave = tid >> 6, lane = tid & 63, lrow = lane & 31, lhalf = lane >> 5;
    const int m0 = blockIdx.x * 64;

    // ---- stage A (spikes) ----
    {
        const int r = tid >> 3, k0 = (tid & 7) * 64;
        const signed char* sp = Sb + (size_t)(m0 + r) * HH + k0;
        const int swz = (r & 15) << 4;
#pragma unroll
        for (int q = 0; q < 4; ++q) {
            v4i v = *(const v4i*)(sp + q * 16);
            *(v4i*)&Asm[r * 512 + ((k0 + q * 16) ^ swz)] = v;
        }
    }

    const int col = wave * 32 + lrow;
    const signed char* bptr = W2p + (size_t)col * 512 + lhalf * 16;

    v16i acc[5];
    v4i cbf[5];
#pragma unroll
    for (int j = 0; j < 5; ++j) cbf[j] = *(const v4i*)(bptr + (size_t)j * 131072);

    __syncthreads();

    const double scl[5] = {0x1p-10, 0x1p-17, 0x1p-24, 0x1p-31, 0x1p-38};
#pragma unroll
    for (int p = 0; p < 2; ++p) {
#pragma unroll
        for (int g = 0; g < 5; ++g)
#pragma unroll
            for (int r = 0; r < 16; ++r) acc[g][r] = 0;
        const int arow = p * 32 + lrow;
        const int aswz = (arow & 15) << 4;
#pragma unroll
        for (int ksl = 0; ksl < 16; ++ksl) {     // K=32 slices of 512
            v4i nbf[5];
            const int s = p * 16 + ksl;
            if (s < 31) {
                const int nk = (ksl == 15) ? 0 : ksl + 1;
#pragma unroll
                for (int j = 0; j < 5; ++j)
                    nbf[j] = *(const v4i*)(bptr + (size_t)j * 131072 + nk * 32);
            }
            v4i a = *(const v4i*)&Asm[arow * 512 + ((ksl * 32 + lhalf * 16) ^ aswz)];
#pragma unroll
            for (int j = 0; j < 5; ++j)
                acc[j] = __builtin_amdgcn_mfma_i32_32x32x32_i8(a, cbf[j], acc[j], 0, 0, 0);
#pragma unroll
            for (int j = 0; j < 5; ++j) cbf[j] = nbf[j];
        }
        const double bcol = (double)b2[col];
#pragma unroll
        for (int r = 0; r < 16; ++r) {
            double t = 0.0;
#pragma unroll
            for (int g = 0; g < 5; ++g) t = fma((double)acc[g][r], scl[g], t);
            const double yr = t + bcol;
            const int crow = (r & 3) + 8 * (r >> 2) + 4 * lhalf;
            Yn[(size_t)(m0 + p * 32 + crow) * DD + col] = yr;
            double ps = yr, pq = yr * yr;
#pragma unroll
            for (int m = 1; m < 32; m <<= 1) {
                ps += shfl_xor_d(ps, m);
                pq += shfl_xor_d(pq, m);
            }
            if (lrow == 0) {
                RSs[wave][p * 32 + crow] = ps;
                RQs[wave][p * 32 + crow] = pq;
            }
        }
    }
    __syncthreads();
    if (tid < 64) {
        double Ssum = 0.0, Qsum = 0.0;
#pragma unroll
        for (int w = 0; w < 8; ++w) { Ssum += RSs[w][tid]; Qsum += RQs[w][tid]; }
        const double mu = Ssum * (1.0 / 256.0);
        const double var = Qsum * (1.0 / 256.0) - mu * mu;
        MUIV2[m0 + tid] = make_double2(mu, 1.0 / sqrt(var + 1e-5));
    }
}

// ---------------------------------------------------------------------------
// LIF2: apply LN2 + fp64 LIF + residual. out = x + spike. 64 thr, 128 blocks.
// ---------------------------------------------------------------------------
__global__ __launch_bounds__(64) void lif2_k(const double* __restrict__ Yn,
                                             const double2* __restrict__ MUIV,
                                             const float* __restrict__ g2,
                                             const float* __restrict__ be2,
                                             const float* __restrict__ X,
                                             float* __restrict__ out) {
    const int b = blockIdx.x >> 2;
    const int d = (blockIdx.x & 3) * 64 + threadIdx.x;
    __shared__ double2 MI[4][16];
    const double* src = Yn + (size_t)b * TT * DD + d;
    const float* xs = X + (size_t)b * TT * DD + d;
    float* dst = out + (size_t)b * TT * DD + d;
    const double gg = (double)g2[d], be = (double)be2[d];
    if (threadIdx.x < 48)
        MI[threadIdx.x >> 4][threadIdx.x & 15] = MUIV[(size_t)b * TT + threadIdx.x];
    double bufy[4][16];
    float bufx[4][16];
#pragma unroll
    for (int gq = 0; gq < 3; ++gq)
#pragma unroll
        for (int t = 0; t < 16; ++t) {
            bufy[gq][t] = src[(size_t)(gq * 16 + t) * DD];
            bufx[gq][t] = xs[(size_t)(gq * 16 + t) * DD];
        }
    __syncthreads();
    double v = 0.0;
    for (int g4 = 0; g4 < 64; g4 += 4) {
#pragma unroll
        for (int u = 0; u < 4; ++u) {
            const int g = g4 + u;
            __syncthreads();
            if (g + 3 < 64) {
                if (threadIdx.x < 16)
                    MI[(g + 3) & 3][threadIdx.x] =
                        MUIV[(size_t)b * TT + (g + 3) * 16 + threadIdx.x];
#pragma unroll
                for (int t = 0; t < 16; ++t) {
                    bufy[(u + 3) & 3][t] = src[(size_t)((g + 3) * 16 + t) * DD];
                    bufx[(u + 3) & 3][t] = xs[(size_t)((g + 3) * 16 + t) * DD];
                }
            }
#pragma unroll
            for (int t = 0; t < 16; ++t) {
                const double2 mi = MI[g & 3][t];
                const double x = (bufy[u][t] - mi.x) * mi.y * gg + be;
                v += (x - v) * 0.5;
                const bool sp = (v >= 1.0);
                __builtin_nontemporal_store(bufx[u][t] + (sp ? 1.0f : 0.0f),
                                            &dst[(size_t)(g * 16 + t) * DD]);
                if (sp) v = 0.0;
            }
        }
    }
}

extern "C" void kernel_launch(void* const* d_in, const int* in_sizes, int n_in,
                              void* d_out, int out_size, void* d_ws, size_t ws_size,
                              hipStream_t stream) {
    const float* x   = (const float*)d_in[0];
    const float* W1  = (const float*)d_in[1];
    const float* b1  = (const float*)d_in[2];
    const float* g1  = (const float*)d_in[3];
    const float* be1 = (const float*)d_in[4];
    const float* W2  = (const float*)d_in[5];
    const float* b2  = (const float*)d_in[6];
    const float* g2  = (const float*)d_in[7];
    const float* be2 = (const float*)d_in[8];
    float* out = (float*)d_out;

    char* ws = (char*)d_ws;
    signed char* W1p = (signed char*)ws;                          // 640 KB
    signed char* W2p = (signed char*)(ws + (1ull << 20));         // 640 KB
    double*      Hn  = (double*)(ws + (2ull << 20));              // 128 MB -> 130
    signed char* Sb  = (signed char*)(ws + (130ull << 20));       // 16 MB  -> 146
    double*      Yn  = (double*)(ws + (146ull << 20));            // 64 MB  -> 210
    // transient aliases inside the Yn region (dead before gemm2 writes Yn):
    signed char* Xp    = (signed char*)(ws + (146ull << 20));     // 40 MB
    double*      PS1w  = (double*)(ws + (186ull << 20));          // 4 MB
    double*      PQ1w  = (double*)(ws + (190ull << 20));          // 4 MB
    double2*     MUIV1 = (double2*)(ws + (194ull << 20));         // 512 KB
    double2*     MUIV2 = (double2*)(ws + (210ull << 20));         // 512 KB
    // total ~210.5 MB

    prep_w_k<<<dim3(512), dim3(256), 0, stream>>>(W1, W2, W1p, W2p);

    for (int c = 0; c < 2; ++c) {
        const float* xc = x + (size_t)c * CM * DD;
        float* outc = out + (size_t)c * CM * DD;
        split_x_k<<<dim3(8192), dim3(256), 0, stream>>>(xc, Xp);
        gemm1_i8<<<dim3(2, CM / 64), dim3(512), 0, stream>>>(Xp, W1p, b1, Hn, PS1w, PQ1w);
        stats1_fin<<<dim3(CM / 256), dim3(256), 0, stream>>>(PS1w, PQ1w, MUIV1);
        lif1_k<<<dim3(CB * 8), dim3(64), 0, stream>>>(Hn, MUIV1, g1, be1, Sb);
        gemm2_i8<<<dim3(CM / 64), dim3(512), 0, stream>>>(Sb, W2p, b2, Yn, MUIV2);
        lif2_k<<<dim3(CB * 4), dim3(64), 0, stream>>>(Yn, MUIV2, g2, be2, xc, outc);
    }
}

// Round 9
// 715.195 us; speedup vs baseline: 1.5646x; 1.0908x over previous
//
#include <hip/hip_runtime.h>

typedef int   v4i __attribute__((ext_vector_type(4)));
typedef int  v16i __attribute__((ext_vector_type(16)));
typedef float v4f __attribute__((ext_vector_type(4)));

#define TT 1024
#define DD 256
#define HH 512
#define CB 32
#define CM (CB*TT)   // 32768 rows per chunk

static __device__ __forceinline__ double shfl_xor_d(double x, int m) {
    union { double d; int u[2]; } a; a.d = x;
    a.u[0] = __shfl_xor(a.u[0], m);
    a.u[1] = __shfl_xor(a.u[1], m);
    return a.d;
}

// ---------------------------------------------------------------------------
// prep_w: split W1 [512][256] and W2 [256][512] into 5 signed-digit i8 planes.
// ---------------------------------------------------------------------------
__global__ __launch_bounds__(256) void prep_w_k(const float* __restrict__ W1,
                                                const float* __restrict__ W2,
                                                signed char* __restrict__ W1p,
                                                signed char* __restrict__ W2p) {
    int i = blockIdx.x * 256 + threadIdx.x;   // 0..131071
    {
        double a = (double)W1[i];
        double inv = 1024.0, s = 1.0 / 1024.0;
#pragma unroll
        for (int p = 0; p < 5; ++p) {
            int d = (int)(a * inv);
            a -= d * s;
            W1p[(size_t)p * 131072 + i] = (signed char)d;
            inv *= 128.0; s *= (1.0 / 128.0);
        }
    }
    {
        double a = (double)W2[i];
        double inv = 1024.0, s = 1.0 / 1024.0;
#pragma unroll
        for (int p = 0; p < 5; ++p) {
            int d = (int)(a * inv);
            a -= d * s;
            W2p[(size_t)p * 131072 + i] = (signed char)d;
            inv *= 128.0; s *= (1.0 / 128.0);
        }
    }
}

// ---------------------------------------------------------------------------
// split_x: x chunk [CM][256] f32 -> 5 digit planes i8 (exact pow2/trunc ops).
// ---------------------------------------------------------------------------
__global__ __launch_bounds__(256) void split_x_k(const float* __restrict__ xc,
                                                 signed char* __restrict__ Xp) {
    int gid = blockIdx.x * 256 + threadIdx.x;   // 0 .. CM*64-1
    int e0 = gid * 4;
    v4f xv = *(const v4f*)(xc + e0);
    int dg[4][5];
#pragma unroll
    for (int e = 0; e < 4; ++e) {
        float a = xv[e];
        float inv = 8.0f, s = 0.125f;
#pragma unroll
        for (int p = 0; p < 5; ++p) {
            int d = (int)(a * inv);
            a -= (float)d * s;
            dg[e][p] = d;
            inv *= 128.0f; s *= (1.0f / 128.0f);
        }
    }
#pragma unroll
    for (int p = 0; p < 5; ++p) {
        int pk = (dg[0][p] & 255) | ((dg[1][p] & 255) << 8) |
                 ((dg[2][p] & 255) << 16) | ((dg[3][p] & 255) << 24);
        *(int*)(Xp + (size_t)p * ((size_t)CM * 256) + e0) = pk;
    }
}

// ---------------------------------------------------------------------------
// GEMM1: raw H = x @ W1^T + b1 (f64) + per-wave row partials (sum,sumsq).
// 256 thr = 4 waves (1m x 4n), tile 32 rows x 256 cols (grid x2 col-halves),
// 2 col-phases. A: 5 planes, 40 KB swizzled LDS -> 2 blocks/CU co-resident.
// B: direct global->VGPR, depth-2 prefetch ring b[3][5].
// ---------------------------------------------------------------------------
__global__ __launch_bounds__(256, 2) void gemm1_i8(
    const signed char* __restrict__ Xp, const signed char* __restrict__ W1p,
    const float* __restrict__ b1, double* __restrict__ Hn,
    double* __restrict__ PS1w, double* __restrict__ PQ1w) {
    __shared__ signed char Asm[5 * 8192];           // 40 KB

    const int tid = threadIdx.x;
    const int wn = tid >> 6, lane = tid & 63, lrow = lane & 31, lhalf = lane >> 5;
    const int ch = blockIdx.x;           // column half of H (0/1)
    const int m0 = blockIdx.y * 32;

    // ---- stage A: 5 planes x [32][256] from Xp, swizzled ----
    {
        const int r = tid >> 3, k0 = (tid & 7) * 32;
        const int swz = (r & 15) << 4;
#pragma unroll
        for (int p = 0; p < 5; ++p) {
            const signed char* sp = Xp + (size_t)p * ((size_t)CM * 256) +
                                    (size_t)(m0 + r) * 256 + k0;
            v4i v0 = *(const v4i*)(sp);
            v4i v1 = *(const v4i*)(sp + 16);
            *(v4i*)&Asm[p * 8192 + r * 256 + (k0 ^ swz)] = v0;
            *(v4i*)&Asm[p * 8192 + r * 256 + ((k0 + 16) ^ swz)] = v1;
        }
    }

    const int colbase = ch * 256 + wn * 32 + lrow;
    const signed char* bptr = W1p + (size_t)colbase * 256 + lhalf * 16;
    // stage s = p*8 + ksl: B offset = p*32768 (128 cols) + ksl*32 (k) + j*131072

    v4i bf[3][5];
#pragma unroll
    for (int s = 0; s < 2; ++s)
#pragma unroll
        for (int j = 0; j < 5; ++j)
            bf[s][j] = *(const v4i*)(bptr + (size_t)j * 131072 +
                                     (s >> 3) * 32768 + (s & 7) * 32);

    v16i acc[5];

    __syncthreads();   // A ready

    const double scl[5] = {0x1p-13, 0x1p-20, 0x1p-27, 0x1p-34, 0x1p-41};
    const int aswz = (lrow & 15) << 4;

#pragma unroll
    for (int p = 0; p < 2; ++p) {
#pragma unroll
        for (int g = 0; g < 5; ++g)
#pragma unroll
            for (int r = 0; r < 16; ++r) acc[g][r] = 0;
#pragma unroll
        for (int ksl = 0; ksl < 8; ++ksl) {
            const int s = p * 8 + ksl;
            if (s + 2 < 16) {
                const int s2 = s + 2;
#pragma unroll
                for (int j = 0; j < 5; ++j)
                    bf[s2 % 3][j] = *(const v4i*)(bptr + (size_t)j * 131072 +
                                                  (s2 >> 3) * 32768 + (s2 & 7) * 32);
            }
            v4i af[5];
#pragma unroll
            for (int i = 0; i < 5; ++i)
                af[i] = *(const v4i*)&Asm[i * 8192 + lrow * 256 +
                                          ((ksl * 32 + lhalf * 16) ^ aswz)];
#pragma unroll
            for (int j = 0; j < 5; ++j)
#pragma unroll
                for (int i = 0; i + j < 5; ++i)
                    acc[i + j] = __builtin_amdgcn_mfma_i32_32x32x32_i8(
                        af[i], bf[s % 3][j], acc[i + j], 0, 0, 0);
        }
        // ---- retire phase p: exact recombine, store, per-wave partials ----
        const int col = colbase + p * 128;
        const double bcol = (double)b1[col];
        const size_t qbase = (size_t)((ch * 2 + p) * 4 + wn) * CM + m0;
#pragma unroll
        for (int r = 0; r < 16; ++r) {
            double t = 0.0;
#pragma unroll
            for (int g = 0; g < 5; ++g) t = fma((double)acc[g][r], scl[g], t);
            const double hr = t + bcol;
            const int crow = (r & 3) + 8 * (r >> 2) + 4 * lhalf;
            Hn[(size_t)(m0 + crow) * HH + col] = hr;
            double ps = hr, pq = hr * hr;
#pragma unroll
            for (int m = 1; m < 32; m <<= 1) {
                ps += shfl_xor_d(ps, m);
                pq += shfl_xor_d(pq, m);
            }
            if (lrow == 0) {
                PS1w[qbase + crow] = ps;
                PQ1w[qbase + crow] = pq;
            }
        }
    }
}

// ---------------------------------------------------------------------------
// stats1_fin: per-row (mu, iv) for LN1 from the 16 per-wave partials.
// ---------------------------------------------------------------------------
__global__ __launch_bounds__(256) void stats1_fin(const double* __restrict__ PS1w,
                                                  const double* __restrict__ PQ1w,
                                                  double2* __restrict__ MUIV1) {
    int row = blockIdx.x * 256 + threadIdx.x;
    double S = 0.0, Q = 0.0;
#pragma unroll
    for (int q = 0; q < 16; ++q) {
        S += PS1w[(size_t)q * CM + row];
        Q += PQ1w[(size_t)q * CM + row];
    }
    double mu = S * (1.0 / 512.0);
    double var = Q * (1.0 / 512.0) - mu * mu;
    MUIV1[row] = make_double2(mu, 1.0 / sqrt(var + 1e-5));
}

// ---------------------------------------------------------------------------
// LIF1: apply LN1 (mu,iv ring in LDS) + fp64 LIF recurrence -> spikes.
// ---------------------------------------------------------------------------
__global__ __launch_bounds__(64) void lif1_k(const double* __restrict__ Hn,
                                             const double2* __restrict__ MUIV,
                                             const float* __restrict__ g1,
                                             const float* __restrict__ be1,
                                             signed char* __restrict__ S) {
    const int b = blockIdx.x >> 3;
    const int h = (blockIdx.x & 7) * 64 + threadIdx.x;
    __shared__ double2 MI[4][16];
    const double* src = Hn + (size_t)b * TT * HH + h;
    signed char* dst = S + (size_t)b * TT * HH + h;
    const double gg = (double)g1[h], be = (double)be1[h];
    if (threadIdx.x < 48)
        MI[threadIdx.x >> 4][threadIdx.x & 15] = MUIV[(size_t)b * TT + threadIdx.x];
    double buf[4][16];
#pragma unroll
    for (int gq = 0; gq < 3; ++gq)
#pragma unroll
        for (int t = 0; t < 16; ++t)
            buf[gq][t] = src[(size_t)(gq * 16 + t) * HH];
    __syncthreads();
    double v = 0.0;
    for (int g4 = 0; g4 < 64; g4 += 4) {
#pragma unroll
        for (int u = 0; u < 4; ++u) {
            const int g = g4 + u;
            __syncthreads();
            if (g + 3 < 64) {
                if (threadIdx.x < 16)
                    MI[(g + 3) & 3][threadIdx.x] =
                        MUIV[(size_t)b * TT + (g + 3) * 16 + threadIdx.x];
#pragma unroll
                for (int t = 0; t < 16; ++t)
                    buf[(u + 3) & 3][t] = src[(size_t)((g + 3) * 16 + t) * HH];
            }
#pragma unroll
            for (int t = 0; t < 16; ++t) {
                const double2 mi = MI[g & 3][t];
                const double x = (buf[u][t] - mi.x) * mi.y * gg + be;
                v += (x - v) * 0.5;
                const bool sp = (v >= 1.0);
                dst[(size_t)(g * 16 + t) * HH] = sp ? 1 : 0;
                if (sp) v = 0.0;
            }
        }
    }
}

// ---------------------------------------------------------------------------
// GEMM2: raw Y = S @ W2^T + b2 (f64) + in-block (mu,iv) for LN2.
// 256 thr = 4 waves (1m x 4n), tile 32 rows x 256 cols (full rows), 2
// col-phases. A = spikes 16 KB swizzled LDS. B: depth-2 prefetch ring.
// Stats slots [p][wn] keep r8's ascending column summation order.
// ---------------------------------------------------------------------------
__global__ __launch_bounds__(256, 2) void gemm2_i8(
    const signed char* __restrict__ Sb, const signed char* __restrict__ W2p,
    const float* __restrict__ b2, double* __restrict__ Yn,
    double2* __restrict__ MUIV2) {
    __shared__ signed char Asm[32 * 512];         // 16 KB
    __shared__ double RSs[2][4][32], RQs[2][4][32];

    const int tid = threadIdx.x;
    const int wn = tid >> 6, lane = tid & 63, lrow = lane & 31, lhalf = lane >> 5;
    const int m0 = blockIdx.x * 32;

    // ---- stage A (spikes [32][512]) ----
    {
        const int r = tid >> 3, k0 = (tid & 7) * 64;
        const signed char* sp = Sb + (size_t)(m0 + r) * HH + k0;
        const int swz = (r & 15) << 4;
#pragma unroll
        for (int q = 0; q < 4; ++q) {
            v4i v = *(const v4i*)(sp + q * 16);
            *(v4i*)&Asm[r * 512 + ((k0 + q * 16) ^ swz)] = v;
        }
    }

    const signed char* bptr = W2p + (size_t)(wn * 32 + lrow) * 512 + lhalf * 16;
    // stage s = p*16 + ksl: B offset = p*65536 (128 cols) + ksl*32 + j*131072

    v4i bf[3][5];
#pragma unroll
    for (int s = 0; s < 2; ++s)
#pragma unroll
        for (int j = 0; j < 5; ++j)
            bf[s][j] = *(const v4i*)(bptr + (size_t)j * 131072 +
                                     (s >> 4) * 65536 + (s & 15) * 32);

    v16i acc[5];

    __syncthreads();

    const double scl[5] = {0x1p-10, 0x1p-17, 0x1p-24, 0x1p-31, 0x1p-38};
    const int aswz = (lrow & 15) << 4;

#pragma unroll
    for (int p = 0; p < 2; ++p) {
#pragma unroll
        for (int g = 0; g < 5; ++g)
#pragma unroll
            for (int r = 0; r < 16; ++r) acc[g][r] = 0;
#pragma unroll
        for (int ksl = 0; ksl < 16; ++ksl) {
            const int s = p * 16 + ksl;
            if (s + 2 < 32) {
                const int s2 = s + 2;
#pragma unroll
                for (int j = 0; j < 5; ++j)
                    bf[s2 % 3][j] = *(const v4i*)(bptr + (size_t)j * 131072 +
                                                  (s2 >> 4) * 65536 + (s2 & 15) * 32);
            }
            v4i a = *(const v4i*)&Asm[lrow * 512 + ((ksl * 32 + lhalf * 16) ^ aswz)];
#pragma unroll
            for (int j = 0; j < 5; ++j)
                acc[j] = __builtin_amdgcn_mfma_i32_32x32x32_i8(a, bf[s % 3][j], acc[j], 0, 0, 0);
        }
        // ---- retire phase p ----
        const int col = p * 128 + wn * 32 + lrow;
        const double bcol = (double)b2[col];
#pragma unroll
        for (int r = 0; r < 16; ++r) {
            double t = 0.0;
#pragma unroll
            for (int g = 0; g < 5; ++g) t = fma((double)acc[g][r], scl[g], t);
            const double yr = t + bcol;
            const int crow = (r & 3) + 8 * (r >> 2) + 4 * lhalf;
            Yn[(size_t)(m0 + crow) * DD + col] = yr;
            double ps = yr, pq = yr * yr;
#pragma unroll
            for (int m = 1; m < 32; m <<= 1) {
                ps += shfl_xor_d(ps, m);
                pq += shfl_xor_d(pq, m);
            }
            if (lrow == 0) {
                RSs[p][wn][crow] = ps;
                RQs[p][wn][crow] = pq;
            }
        }
    }
    __syncthreads();
    if (tid < 32) {
        double Ssum = 0.0, Qsum = 0.0;
#pragma unroll
        for (int p = 0; p < 2; ++p)
#pragma unroll
            for (int w = 0; w < 4; ++w) { Ssum += RSs[p][w][tid]; Qsum += RQs[p][w][tid]; }
        const double mu = Ssum * (1.0 / 256.0);
        const double var = Qsum * (1.0 / 256.0) - mu * mu;
        MUIV2[m0 + tid] = make_double2(mu, 1.0 / sqrt(var + 1e-5));
    }
}

// ---------------------------------------------------------------------------
// LIF2: apply LN2 + fp64 LIF + residual. out = x + spike.
// ---------------------------------------------------------------------------
__global__ __launch_bounds__(64) void lif2_k(const double* __restrict__ Yn,
                                             const double2* __restrict__ MUIV,
                                             const float* __restrict__ g2,
                                             const float* __restrict__ be2,
                                             const float* __restrict__ X,
                                             float* __restrict__ out) {
    const int b = blockIdx.x >> 2;
    const int d = (blockIdx.x & 3) * 64 + threadIdx.x;
    __shared__ double2 MI[4][16];
    const double* src = Yn + (size_t)b * TT * DD + d;
    const float* xs = X + (size_t)b * TT * DD + d;
    float* dst = out + (size_t)b * TT * DD + d;
    const double gg = (double)g2[d], be = (double)be2[d];
    if (threadIdx.x < 48)
        MI[threadIdx.x >> 4][threadIdx.x & 15] = MUIV[(size_t)b * TT + threadIdx.x];
    double bufy[4][16];
    float bufx[4][16];
#pragma unroll
    for (int gq = 0; gq < 3; ++gq)
#pragma unroll
        for (int t = 0; t < 16; ++t) {
            bufy[gq][t] = src[(size_t)(gq * 16 + t) * DD];
            bufx[gq][t] = xs[(size_t)(gq * 16 + t) * DD];
        }
    __syncthreads();
    double v = 0.0;
    for (int g4 = 0; g4 < 64; g4 += 4) {
#pragma unroll
        for (int u = 0; u < 4; ++u) {
            const int g = g4 + u;
            __syncthreads();
            if (g + 3 < 64) {
                if (threadIdx.x < 16)
                    MI[(g + 3) & 3][threadIdx.x] =
                        MUIV[(size_t)b * TT + (g + 3) * 16 + threadIdx.x];
#pragma unroll
                for (int t = 0; t < 16; ++t) {
                    bufy[(u + 3) & 3][t] = src[(size_t)((g + 3) * 16 + t) * DD];
                    bufx[(u + 3) & 3][t] = xs[(size_t)((g + 3) * 16 + t) * DD];
                }
            }
#pragma unroll
            for (int t = 0; t < 16; ++t) {
                const double2 mi = MI[g & 3][t];
                const double x = (bufy[u][t] - mi.x) * mi.y * gg + be;
                v += (x - v) * 0.5;
                const bool sp = (v >= 1.0);
                __builtin_nontemporal_store(bufx[u][t] + (sp ? 1.0f : 0.0f),
                                            &dst[(size_t)(g * 16 + t) * DD]);
                if (sp) v = 0.0;
            }
        }
    }
}

extern "C" void kernel_launch(void* const* d_in, const int* in_sizes, int n_in,
                              void* d_out, int out_size, void* d_ws, size_t ws_size,
                              hipStream_t stream) {
    const float* x   = (const float*)d_in[0];
    const float* W1  = (const float*)d_in[1];
    const float* b1  = (const float*)d_in[2];
    const float* g1  = (const float*)d_in[3];
    const float* be1 = (const float*)d_in[4];
    const float* W2  = (const float*)d_in[5];
    const float* b2  = (const float*)d_in[6];
    const float* g2  = (const float*)d_in[7];
    const float* be2 = (const float*)d_in[8];
    float* out = (float*)d_out;

    char* ws = (char*)d_ws;
    signed char* W1p = (signed char*)ws;                          // 640 KB
    signed char* W2p = (signed char*)(ws + (1ull << 20));         // 640 KB
    double*      Hn  = (double*)(ws + (2ull << 20));              // 128 MB -> 130
    signed char* Sb  = (signed char*)(ws + (130ull << 20));       // 16 MB  -> 146
    double*      Yn  = (double*)(ws + (146ull << 20));            // 64 MB  -> 210
    // transient aliases inside the Yn region (dead before gemm2 writes Yn):
    signed char* Xp    = (signed char*)(ws + (146ull << 20));     // 40 MB
    double*      PS1w  = (double*)(ws + (186ull << 20));          // 4 MB
    double*      PQ1w  = (double*)(ws + (190ull << 20));          // 4 MB
    double2*     MUIV1 = (double2*)(ws + (194ull << 20));         // 512 KB
    double2*     MUIV2 = (double2*)(ws + (210ull << 20));         // 512 KB

    prep_w_k<<<dim3(512), dim3(256), 0, stream>>>(W1, W2, W1p, W2p);

    for (int c = 0; c < 2; ++c) {
        const float* xc = x + (size_t)c * CM * DD;
        float* outc = out + (size_t)c * CM * DD;
        split_x_k<<<dim3(8192), dim3(256), 0, stream>>>(xc, Xp);
        gemm1_i8<<<dim3(2, CM / 32), dim3(256), 0, stream>>>(Xp, W1p, b1, Hn, PS1w, PQ1w);
        stats1_fin<<<dim3(CM / 256), dim3(256), 0, stream>>>(PS1w, PQ1w, MUIV1);
        lif1_k<<<dim3(CB * 8), dim3(64), 0, stream>>>(Hn, MUIV1, g1, be1, Sb);
        gemm2_i8<<<dim3(CM / 32), dim3(256), 0, stream>>>(Sb, W2p, b2, Yn, MUIV2);
        lif2_k<<<dim3(CB * 4), dim3(64), 0, stream>>>(Yn, MUIV2, g2, be2, xc, outc);
    }
}